// Round 6
// baseline (363.824 us; speedup 1.0000x reference)
//
#include <hip/hip_runtime.h>
#include <stdint.h>

typedef unsigned short u16;
typedef __attribute__((ext_vector_type(8))) __bf16 bf16x8;
typedef __attribute__((ext_vector_type(4))) float f32x4;

__device__ __forceinline__ float bf2f(u16 u){
  unsigned int x = ((unsigned int)u) << 16;
  return __builtin_bit_cast(float, x);
}
__device__ __forceinline__ u16 f2bf(float f){
  unsigned int u = __builtin_bit_cast(unsigned int, f);
  u += 0x7fffu + ((u >> 16) & 1u);   // RNE
  return (u16)(u >> 16);
}

// ------- transpose+convert: out_bf16[C][R] = in_f32[R][C], 64x64 tiles -------
__global__ __launch_bounds__(256) void transpose64(const float* __restrict__ in,
                                                   u16* __restrict__ out,
                                                   int R, int C){
  __shared__ u16 t[64][65];
  const int c0 = blockIdx.x * 64, r0 = blockIdx.y * 64;
  const int tid = threadIdx.x;
  const int rr = tid >> 3;          // 0..31
  const int cc = (tid & 7) * 8;     // 0..56
#pragma unroll
  for (int i = 0; i < 2; i++){
    int r = i * 32 + rr;
    const float* p = in + (size_t)(r0 + r) * C + c0 + cc;
    f32x4 v0 = *(const f32x4*)p;
    f32x4 v1 = *(const f32x4*)(p + 4);
#pragma unroll
    for (int j = 0; j < 4; j++){ t[r][cc + j] = f2bf(v0[j]); t[r][cc + 4 + j] = f2bf(v1[j]); }
  }
  __syncthreads();
#pragma unroll
  for (int i = 0; i < 2; i++){
    int c = i * 32 + rr;
    u16 tmp[8];
#pragma unroll
    for (int j = 0; j < 8; j++) tmp[j] = t[cc + j][c];
    *(bf16x8*)(out + (size_t)(c0 + c) * R + r0 + cc) = *(const bf16x8*)tmp;
  }
}

// ------- vT[bh][d=64][s=2048] = V third of qkv, per-head transposed ----------
__global__ __launch_bounds__(256) void v_transpose(const u16* __restrict__ qkv,
                                                   u16* __restrict__ vT){
  const int S = 2048, LD = 3072;
  __shared__ u16 t[64][65];
  const int bh = blockIdx.y;
  const int b = bh >> 4, h = bh & 15;
  const int s0 = blockIdx.x * 64;
  const u16* src = qkv + (size_t)b * S * LD + 2048 + h * 64;
  const int tid = threadIdx.x;
  const int rr = tid >> 3;          // 0..31
  const int cc = (tid & 7) * 8;     // 0..56
#pragma unroll
  for (int i = 0; i < 2; i++){
    int s = i * 32 + rr;
    bf16x8 v = *(const bf16x8*)(src + (size_t)(s0 + s) * LD + cc);
#pragma unroll
    for (int j = 0; j < 8; j++) t[s][cc + j] = __builtin_bit_cast(u16, (__bf16)v[j]);
  }
  __syncthreads();
  u16* dst = vT + (size_t)bh * 64 * S;
#pragma unroll
  for (int i = 0; i < 2; i++){
    int d = i * 32 + rr;
    u16 tmp[8];
#pragma unroll
    for (int j = 0; j < 8; j++) tmp[j] = t[cc + j][d];
    *(bf16x8*)(dst + (size_t)d * S + s0 + cc) = *(const bf16x8*)tmp;
  }
}

// ---------------- GEMM: C[M][N] = A[M][K] * Bt[N][K]^T + bias ----------------
template<bool AF32, bool OUTF32>
__global__ __launch_bounds__(256, 2) void gemm_bt(const void* __restrict__ Av,
                                                  const u16* __restrict__ Bt,
                                                  const float* __restrict__ bias,
                                                  void* __restrict__ Cv,
                                                  int M, int N, int K){
  __shared__ u16 As[128 * 32];
  __shared__ u16 Bs[128 * 32];
  const int bn = blockIdx.x, bm = blockIdx.y;
  const int tid = threadIdx.x, w = tid >> 6, l = tid & 63;
  const int lo = l & 15, hi = l >> 4;
  const int wr = (w >> 1) * 64, wc = (w & 1) * 64;
  f32x4 acc[4][4] = {};

  for (int k0 = 0; k0 < K; k0 += 32){
#pragma unroll
    for (int i = 0; i < 2; i++){
      int cid = i * 256 + tid;          // 512 chunks of 8 elems per tile
      int row = cid >> 2, cd = cid & 3;
      int cs = cd ^ ((row >> 1) & 3);   // source chunk (swizzle involution)
      if (AF32){
        const float* ap = (const float*)Av + (size_t)(bm * 128 + row) * K + k0 + cs * 8;
        f32x4 a0 = *(const f32x4*)ap;
        f32x4 a1 = *(const f32x4*)(ap + 4);
        u16 tmp[8];
#pragma unroll
        for (int j = 0; j < 4; j++){ tmp[j] = f2bf(a0[j]); tmp[4 + j] = f2bf(a1[j]); }
        *(bf16x8*)((char*)As + row * 64 + cd * 16) = *(const bf16x8*)tmp;
      } else {
        bf16x8 av = *(const bf16x8*)((const u16*)Av + (size_t)(bm * 128 + row) * K + k0 + cs * 8);
        *(bf16x8*)((char*)As + row * 64 + cd * 16) = av;
      }
      bf16x8 bv = *(const bf16x8*)(Bt + (size_t)(bn * 128 + row) * K + k0 + cs * 8);
      *(bf16x8*)((char*)Bs + row * 64 + cd * 16) = bv;
    }
    __syncthreads();
    bf16x8 a[4], b[4];
#pragma unroll
    for (int mi = 0; mi < 4; mi++){
      int row = wr + mi * 16 + lo;
      unsigned byte = (unsigned)(row * 64 + hi * 16) ^ (((row >> 1) & 3) << 4);
      a[mi] = *(const bf16x8*)((const char*)As + byte);
    }
#pragma unroll
    for (int ni = 0; ni < 4; ni++){
      int row = wc + ni * 16 + lo;
      unsigned byte = (unsigned)(row * 64 + hi * 16) ^ (((row >> 1) & 3) << 4);
      b[ni] = *(const bf16x8*)((const char*)Bs + byte);
    }
#pragma unroll
    for (int mi = 0; mi < 4; mi++)
#pragma unroll
      for (int ni = 0; ni < 4; ni++)
        acc[mi][ni] = __builtin_amdgcn_mfma_f32_16x16x32_bf16(a[mi], b[ni], acc[mi][ni], 0, 0, 0);
    __syncthreads();
  }
#pragma unroll
  for (int mi = 0; mi < 4; mi++){
#pragma unroll
    for (int r = 0; r < 4; r++){
      int grow = bm * 128 + wr + mi * 16 + hi * 4 + r;
#pragma unroll
      for (int ni = 0; ni < 4; ni++){
        int col = ni * 16 + lo;
        float v = acc[mi][ni][r] + bias[bn * 128 + wc + col];
        if (OUTF32)
          ((float*)Cv)[(size_t)grow * N + bn * 128 + wc + col] = v;
        else
          ((u16*)Cv)[(size_t)grow * N + bn * 128 + wc + col] = f2bf(v);
      }
    }
  }
}

// ---------------- RoPE in-place on q,k thirds of qkv[4096][3072] -------------
__global__ __launch_bounds__(256) void rope_inplace(u16* __restrict__ qkv,
                                                    const float* __restrict__ cosb,
                                                    const float* __restrict__ sinb){
  int tid = blockIdx.x * 256 + threadIdx.x;  // 4096*16*32 threads
  int i = tid & 31;
  int h = (tid >> 5) & 15;
  int m = tid >> 9;
  int s = m & 2047;
  u16* row = qkv + (size_t)m * 3072;
  float c  = cosb[s * 32 + i];
  float sn = sinb[s * 32 + i];
  int qi = h * 64 + 2 * i;
  float e = bf2f(row[qi]), o = bf2f(row[qi + 1]);
  row[qi]     = f2bf(e * c - o * sn);
  row[qi + 1] = f2bf(e * sn + o * c);
  int ki = 1024 + qi;
  e = bf2f(row[ki]); o = bf2f(row[ki + 1]);
  row[ki]     = f2bf(e * c - o * sn);
  row[ki + 1] = f2bf(e * sn + o * c);
}

// ---------------- flash attention: barrier-free + 2-deep K prefetch ----------
// 4 waves/block; wave w owns q-tile qt (16 rows), reversed order (heavy first).
// Swapped QK^T (S^T): lane(lo,hi) -> q=lo, keys f*16+hi*4+r.
// kA/kB: double-buffered K fragment sets (prefetch next tile during current).
// V frags issued before QK mfma -> covered by QK+softmax until PV.
__global__ __launch_bounds__(256, 3) void flash_attn(const u16* __restrict__ qkv,
                                                     const u16* __restrict__ vT,
                                                     u16* __restrict__ Oout){
  const int S = 2048, LD = 3072;
  const int bh = blockIdx.y;
  const int b = bh >> 4, h = bh & 15;
  const u16* base = qkv + (size_t)b * S * LD;
  const u16* Qp = base + h * 64;
  const u16* Kp = base + 1024 + h * 64;
  const u16* Vb = vT + (size_t)bh * 64 * S;   // [d][s]
  const int tid = threadIdx.x, w = tid >> 6, l = tid & 63;
  const int lo = l & 15, hi = l >> 4;
  __shared__ u16 Ps[4][16 * 72];              // per-wave, 144B row stride
  const int qt = (31 - blockIdx.x) * 4 + w;   // reversed: heavy blocks first
  const int q0 = qt * 16;
  const int qrow = q0 + lo;

  bf16x8 qf[2];
#pragma unroll
  for (int c = 0; c < 2; c++)
    qf[c] = *(const bf16x8*)(Qp + (size_t)qrow * LD + c * 32 + hi * 8);

  f32x4 o[4] = {};
  float m_r = -1e30f, l_r = 0.f;

  auto loadK = [&](bf16x8 (&kb)[2][4], int kt){
#pragma unroll
    for (int c = 0; c < 2; c++)
#pragma unroll
      for (int f = 0; f < 4; f++)
        kb[c][f] = *(const bf16x8*)(Kp + (size_t)(kt * 64 + f * 16 + lo) * LD + c * 32 + hi * 8);
  };

  auto body = [&](bf16x8 (&kb)[2][4], int kt){
    // ---- V^T B-frags issued first (consumed at PV, covered by QK+softmax) ----
    bf16x8 vb[2][4];
#pragma unroll
    for (int c = 0; c < 2; c++)
#pragma unroll
      for (int fd = 0; fd < 4; fd++)
        vb[c][fd] = *(const bf16x8*)(Vb + (size_t)(fd * 16 + lo) * S + kt * 64 + c * 32 + hi * 8);
    // ---- S^T = K · Q^T ----
    f32x4 sa[4] = {};
#pragma unroll
    for (int c = 0; c < 2; c++)
#pragma unroll
      for (int f = 0; f < 4; f++)
        sa[f] = __builtin_amdgcn_mfma_f32_16x16x32_bf16(kb[c][f], qf[c], sa[f], 0, 0, 0);
    // ---- scale + causal mask ----
#pragma unroll
    for (int f = 0; f < 4; f++){
      int key0 = kt * 64 + f * 16 + hi * 4;
#pragma unroll
      for (int r = 0; r < 4; r++)
        sa[f][r] = (key0 + r <= qrow) ? sa[f][r] * 0.125f : -1e30f;
    }
    // ---- online softmax for q=lo ----
    float pmax = sa[0][0];
#pragma unroll
    for (int f = 0; f < 4; f++)
#pragma unroll
      for (int r = 0; r < 4; r++) pmax = fmaxf(pmax, sa[f][r]);
    pmax = fmaxf(pmax, __shfl_xor(pmax, 16, 64));
    pmax = fmaxf(pmax, __shfl_xor(pmax, 32, 64));
    float mnew = fmaxf(m_r, pmax);
    float corr = __expf(m_r - mnew);
    m_r = mnew;
    float psum = 0.f;
    float p[4][4];
#pragma unroll
    for (int f = 0; f < 4; f++)
#pragma unroll
      for (int r = 0; r < 4; r++){
        float pv = __expf(sa[f][r] - mnew);
        p[f][r] = pv;
        psum += pv;
      }
    psum += __shfl_xor(psum, 16, 64);
    psum += __shfl_xor(psum, 32, 64);
    l_r = l_r * corr + psum;
    // ---- P[q=lo][k] -> per-wave LDS, read back as A-frags ----
#pragma unroll
    for (int f = 0; f < 4; f++)
#pragma unroll
      for (int r = 0; r < 4; r++){
        int k = f * 16 + hi * 4 + r;
        *(u16*)((char*)&Ps[w][0] + lo * 144 + k * 2) = f2bf(p[f][r]);
      }
    // ---- rescale O ----
    float corr_q[4];
#pragma unroll
    for (int r = 0; r < 4; r++) corr_q[r] = __shfl(corr, hi * 4 + r, 64);
#pragma unroll
    for (int fd = 0; fd < 4; fd++)
#pragma unroll
      for (int r = 0; r < 4; r++) o[fd][r] *= corr_q[r];
    bf16x8 pa[2];
#pragma unroll
    for (int c = 0; c < 2; c++)
      pa[c] = *(const bf16x8*)((const char*)&Ps[w][0] + lo * 144 + c * 64 + hi * 16);
    // ---- O += P V ----
#pragma unroll
    for (int fd = 0; fd < 4; fd++)
#pragma unroll
      for (int c = 0; c < 2; c++)
        o[fd] = __builtin_amdgcn_mfma_f32_16x16x32_bf16(pa[c], vb[c][fd], o[fd], 0, 0, 0);
  };

  const int nkt = (qt >> 2) + 1;
  bf16x8 kA[2][4], kB[2][4];
  loadK(kA, 0);
  int kt = 0;
  while (true){
    if (kt + 1 < nkt) loadK(kB, kt + 1);     // prefetch next K tile
    body(kA, kt);
    kt++;
    if (kt >= nkt) break;
    if (kt + 1 < nkt) loadK(kA, kt + 1);
    body(kB, kt);
    kt++;
    if (kt >= nkt) break;
  }
  // ---- normalize + store: row q=hi*4+r, col d=fd*16+lo ----
  float linv = 1.0f / l_r;
  float inv_q[4];
#pragma unroll
  for (int r = 0; r < 4; r++) inv_q[r] = __shfl(linv, hi * 4 + r, 64);
#pragma unroll
  for (int r = 0; r < 4; r++){
    int srow = q0 + hi * 4 + r;
    u16* orow = Oout + (size_t)(b * S + srow) * 1024 + h * 64;
#pragma unroll
    for (int fd = 0; fd < 4; fd++)
      orow[fd * 16 + lo] = f2bf(o[fd][r] * inv_q[r]);
  }
}

extern "C" void kernel_launch(void* const* d_in, const int* in_sizes, int n_in,
                              void* d_out, int out_size, void* d_ws, size_t ws_size,
                              hipStream_t stream){
  const float* x     = (const float*)d_in[0];
  const float* w_qkv = (const float*)d_in[1];
  const float* b_qkv = (const float*)d_in[2];
  const float* w_out = (const float*)d_in[3];
  const float* b_out = (const float*)d_in[4];
  const float* cosb  = (const float*)d_in[5];
  const float* sinb  = (const float*)d_in[6];
  // d_in[7] = mask: causal, implemented analytically.
  float* out = (float*)d_out;
  char* ws = (char*)d_ws;
  u16* qkv  = (u16*)(ws);               // bf16 [4096][3072]   25.2 MB
  u16* attn = (u16*)(ws + 25165824);    // bf16 [4096][1024]    8.4 MB
  u16* wT2  = (u16*)(ws + 33554432);    // w_out^T bf16 [1024][1024]  2.1 MB
  u16* wT1  = (u16*)(ws + 35651584);    // w_qkv^T bf16 [3072][1024]  6.3 MB
  u16* vT   = (u16*)(ws + 35651584);    // vT [32][64][2048] 8.4 MB — overlaps
                                        // wT1 (dead after GEMM1)

  transpose64<<<dim3(48, 16), 256, 0, stream>>>(w_qkv, wT1, 1024, 3072);
  transpose64<<<dim3(16, 16), 256, 0, stream>>>(w_out, wT2, 1024, 1024);
  gemm_bt<true , false><<<dim3(24, 32), 256, 0, stream>>>(x,    wT1, b_qkv, qkv, 4096, 3072, 1024);
  rope_inplace<<<8192, 256, 0, stream>>>(qkv, cosb, sinb);
  v_transpose<<<dim3(32, 32), 256, 0, stream>>>(qkv, vT);
  flash_attn<<<dim3(32, 32), 256, 0, stream>>>(qkv, vT, attn);
  gemm_bt<false, true ><<<dim3(8, 32), 256, 0, stream>>>(attn, wT2, b_out, out, 4096, 1024, 1024);
}

// Round 7
// 212.156 us; speedup vs baseline: 1.7149x; 1.7149x over previous
//
#include <hip/hip_runtime.h>
#include <stdint.h>

typedef unsigned short u16;
typedef __attribute__((ext_vector_type(8))) __bf16 bf16x8;
typedef __attribute__((ext_vector_type(4))) float f32x4;

__device__ __forceinline__ float bf2f(u16 u){
  unsigned int x = ((unsigned int)u) << 16;
  return __builtin_bit_cast(float, x);
}
__device__ __forceinline__ u16 f2bf(float f){
  unsigned int u = __builtin_bit_cast(unsigned int, f);
  u += 0x7fffu + ((u >> 16) & 1u);   // RNE
  return (u16)(u >> 16);
}
// global -> LDS direct DMA, 16B/lane. LDS dest = wave-uniform base (+lane*16).
// Proper addrspace casts (addrspacecast), NOT integer truncation.
__device__ __forceinline__ void lds_load16(const void* g, void* l){
  __builtin_amdgcn_global_load_lds(
      (const __attribute__((address_space(1))) unsigned int*)g,
      (__attribute__((address_space(3))) unsigned int*)l, 16, 0, 0);
}

// ------- transpose+convert: out_bf16[C][R] = in_f32[R][C], 64x64 tiles -------
__global__ __launch_bounds__(256) void transpose64(const float* __restrict__ in,
                                                   u16* __restrict__ out,
                                                   int R, int C){
  __shared__ u16 t[64][65];
  const int c0 = blockIdx.x * 64, r0 = blockIdx.y * 64;
  const int tid = threadIdx.x;
  const int rr = tid >> 3;          // 0..31
  const int cc = (tid & 7) * 8;     // 0..56
#pragma unroll
  for (int i = 0; i < 2; i++){
    int r = i * 32 + rr;
    const float* p = in + (size_t)(r0 + r) * C + c0 + cc;
    f32x4 v0 = *(const f32x4*)p;
    f32x4 v1 = *(const f32x4*)(p + 4);
#pragma unroll
    for (int j = 0; j < 4; j++){ t[r][cc + j] = f2bf(v0[j]); t[r][cc + 4 + j] = f2bf(v1[j]); }
  }
  __syncthreads();
#pragma unroll
  for (int i = 0; i < 2; i++){
    int c = i * 32 + rr;
    u16 tmp[8];
#pragma unroll
    for (int j = 0; j < 8; j++) tmp[j] = t[cc + j][c];
    *(bf16x8*)(out + (size_t)(c0 + c) * R + r0 + cc) = *(const bf16x8*)tmp;
  }
}

// ------- vT[bh][d=64][s=2048] = V third of qkv, per-head transposed ----------
__global__ __launch_bounds__(256) void v_transpose(const u16* __restrict__ qkv,
                                                   u16* __restrict__ vT){
  const int S = 2048, LD = 3072;
  __shared__ u16 t[64][65];
  const int bh = blockIdx.y;
  const int b = bh >> 4, h = bh & 15;
  const int s0 = blockIdx.x * 64;
  const u16* src = qkv + (size_t)b * S * LD + 2048 + h * 64;
  const int tid = threadIdx.x;
  const int rr = tid >> 3;          // 0..31
  const int cc = (tid & 7) * 8;     // 0..56
#pragma unroll
  for (int i = 0; i < 2; i++){
    int s = i * 32 + rr;
    bf16x8 v = *(const bf16x8*)(src + (size_t)(s0 + s) * LD + cc);
#pragma unroll
    for (int j = 0; j < 8; j++) t[s][cc + j] = __builtin_bit_cast(u16, (__bf16)v[j]);
  }
  __syncthreads();
  u16* dst = vT + (size_t)bh * 64 * S;
#pragma unroll
  for (int i = 0; i < 2; i++){
    int d = i * 32 + rr;
    u16 tmp[8];
#pragma unroll
    for (int j = 0; j < 8; j++) tmp[j] = t[cc + j][d];
    *(bf16x8*)(dst + (size_t)d * S + s0 + cc) = *(const bf16x8*)tmp;
  }
}

// ---------------- GEMM: C[M][N] = A[M][K] * Bt[N][K]^T + bias ----------------
template<bool AF32, bool OUTF32>
__global__ __launch_bounds__(256, 2) void gemm_bt(const void* __restrict__ Av,
                                                  const u16* __restrict__ Bt,
                                                  const float* __restrict__ bias,
                                                  void* __restrict__ Cv,
                                                  int M, int N, int K){
  __shared__ u16 As[128 * 32];
  __shared__ u16 Bs[128 * 32];
  const int bn = blockIdx.x, bm = blockIdx.y;
  const int tid = threadIdx.x, w = tid >> 6, l = tid & 63;
  const int lo = l & 15, hi = l >> 4;
  const int wr = (w >> 1) * 64, wc = (w & 1) * 64;
  f32x4 acc[4][4] = {};

  for (int k0 = 0; k0 < K; k0 += 32){
#pragma unroll
    for (int i = 0; i < 2; i++){
      int cid = i * 256 + tid;          // 512 chunks of 8 elems per tile
      int row = cid >> 2, cd = cid & 3;
      int cs = cd ^ ((row >> 1) & 3);   // source chunk (swizzle involution)
      if (AF32){
        const float* ap = (const float*)Av + (size_t)(bm * 128 + row) * K + k0 + cs * 8;
        f32x4 a0 = *(const f32x4*)ap;
        f32x4 a1 = *(const f32x4*)(ap + 4);
        u16 tmp[8];
#pragma unroll
        for (int j = 0; j < 4; j++){ tmp[j] = f2bf(a0[j]); tmp[4 + j] = f2bf(a1[j]); }
        *(bf16x8*)((char*)As + row * 64 + cd * 16) = *(const bf16x8*)tmp;
      } else {
        bf16x8 av = *(const bf16x8*)((const u16*)Av + (size_t)(bm * 128 + row) * K + k0 + cs * 8);
        *(bf16x8*)((char*)As + row * 64 + cd * 16) = av;
      }
      bf16x8 bv = *(const bf16x8*)(Bt + (size_t)(bn * 128 + row) * K + k0 + cs * 8);
      *(bf16x8*)((char*)Bs + row * 64 + cd * 16) = bv;
    }
    __syncthreads();
    bf16x8 a[4], b[4];
#pragma unroll
    for (int mi = 0; mi < 4; mi++){
      int row = wr + mi * 16 + lo;
      unsigned byte = (unsigned)(row * 64 + hi * 16) ^ (((row >> 1) & 3) << 4);
      a[mi] = *(const bf16x8*)((const char*)As + byte);
    }
#pragma unroll
    for (int ni = 0; ni < 4; ni++){
      int row = wc + ni * 16 + lo;
      unsigned byte = (unsigned)(row * 64 + hi * 16) ^ (((row >> 1) & 3) << 4);
      b[ni] = *(const bf16x8*)((const char*)Bs + byte);
    }
#pragma unroll
    for (int mi = 0; mi < 4; mi++)
#pragma unroll
      for (int ni = 0; ni < 4; ni++)
        acc[mi][ni] = __builtin_amdgcn_mfma_f32_16x16x32_bf16(a[mi], b[ni], acc[mi][ni], 0, 0, 0);
    __syncthreads();
  }
#pragma unroll
  for (int mi = 0; mi < 4; mi++){
#pragma unroll
    for (int r = 0; r < 4; r++){
      int grow = bm * 128 + wr + mi * 16 + hi * 4 + r;
#pragma unroll
      for (int ni = 0; ni < 4; ni++){
        int col = ni * 16 + lo;
        float v = acc[mi][ni][r] + bias[bn * 128 + wc + col];
        if (OUTF32)
          ((float*)Cv)[(size_t)grow * N + bn * 128 + wc + col] = v;
        else
          ((u16*)Cv)[(size_t)grow * N + bn * 128 + wc + col] = f2bf(v);
      }
    }
  }
}

// ---------------- RoPE in-place on q,k thirds of qkv[4096][3072] -------------
__global__ __launch_bounds__(256) void rope_inplace(u16* __restrict__ qkv,
                                                    const float* __restrict__ cosb,
                                                    const float* __restrict__ sinb){
  int tid = blockIdx.x * 256 + threadIdx.x;  // 4096*16*32 threads
  int i = tid & 31;
  int h = (tid >> 5) & 15;
  int m = tid >> 9;
  int s = m & 2047;
  u16* row = qkv + (size_t)m * 3072;
  float c  = cosb[s * 32 + i];
  float sn = sinb[s * 32 + i];
  int qi = h * 64 + 2 * i;
  float e = bf2f(row[qi]), o = bf2f(row[qi + 1]);
  row[qi]     = f2bf(e * c - o * sn);
  row[qi + 1] = f2bf(e * sn + o * c);
  int ki = 1024 + qi;
  e = bf2f(row[ki]); o = bf2f(row[ki + 1]);
  row[ki]     = f2bf(e * c - o * sn);
  row[ki + 1] = f2bf(e * sn + o * c);
}

// ------------- flash attention: DMA double-buffered K, 2-phase loop ----------
// 4 waves/block, block owns 64 q-rows (wave w: rows q0+w*16+lo), reversed order.
// Per kt: issue DMA stage of K(kt+1) into buf[cur^1], compute from buf[cur]
// (V^T frags global->reg issued first), ONE barrier per tile (drains vm+lgkm).
// No cross-iteration register buffers (r6 spill lesson) — only LDS persists.
__global__ __launch_bounds__(256, 4) void flash_attn(const u16* __restrict__ qkv,
                                                     const u16* __restrict__ vT,
                                                     u16* __restrict__ Oout){
  const int S = 2048, LD = 3072;
  const int bh = blockIdx.y;
  const int b = bh >> 4, h = bh & 15;
  const u16* base = qkv + (size_t)b * S * LD;
  const u16* Qp = base + h * 64;
  const u16* Kp = base + 1024 + h * 64;
  const u16* Vb = vT + (size_t)bh * 64 * S;   // [d][s]
  const int tid = threadIdx.x, w = tid >> 6, l = tid & 63;
  const int lo = l & 15, hi = l >> 4;
  __shared__ u16 Ks[2][64 * 64];              // double-buffered K tile
  __shared__ u16 Ps[4][16 * 72];              // per-wave P, 144B row stride
  const int qt = 31 - blockIdx.x;             // reversed: heavy blocks first
  const int q0 = qt * 64;
  const int qrow = q0 + w * 16 + lo;

  bf16x8 qf[2];
#pragma unroll
  for (int c = 0; c < 2; c++)
    qf[c] = *(const bf16x8*)(Qp + (size_t)qrow * LD + c * 32 + hi * 8);

  f32x4 o[4] = {};
  float m_r = -1e30f, l_r = 0.f;

  // DMA stage: wave w, issue i covers rows (i*4+w)*8 .. +8 (1KB linear LDS).
  // LDS(row, cd) = global chunk (cd ^ (row&7)); lane l -> row+=l>>3, cd=l&7.
  const int srow8 = l >> 3, scd = l & 7;
  const int scs = scd ^ srow8;                // source chunk (row&7 == l>>3)

  auto stageK = [&](int kt, int bufi){
#pragma unroll
    for (int i = 0; i < 2; i++){
      int base_row = (i * 4 + w) * 8;
      lds_load16(Kp + (size_t)(kt * 64 + base_row + srow8) * LD + scs * 8,
                 (char*)&Ks[bufi][0] + base_row * 128);
    }
  };

  const int nkt = qt + 1;
  stageK(0, 0);
  __syncthreads();

  int cur = 0;
  for (int kt = 0; kt < nkt; kt++){
    if (kt + 1 < nkt) stageK(kt + 1, cur ^ 1);
    // ---- V^T B-frags issued early (global, L2-resident) ----
    bf16x8 vb[2][4];
#pragma unroll
    for (int c = 0; c < 2; c++)
#pragma unroll
      for (int fd = 0; fd < 4; fd++)
        vb[c][fd] = *(const bf16x8*)(Vb + (size_t)(fd * 16 + lo) * S + kt * 64 + c * 32 + hi * 8);
    // ---- S^T = K · Q^T (swizzled b128 reads from current buffer) ----
    f32x4 sa[4] = {};
#pragma unroll
    for (int c = 0; c < 2; c++)
#pragma unroll
      for (int f = 0; f < 4; f++){
        int srow = f * 16 + lo;
        unsigned byte = ((unsigned)(srow * 128 + c * 64 + hi * 16)) ^ ((srow & 7) << 4);
        bf16x8 kb = *(const bf16x8*)((const char*)&Ks[cur][0] + byte);
        sa[f] = __builtin_amdgcn_mfma_f32_16x16x32_bf16(kb, qf[c], sa[f], 0, 0, 0);
      }
    // ---- scale + causal mask ----
#pragma unroll
    for (int f = 0; f < 4; f++){
      int key0 = kt * 64 + f * 16 + hi * 4;
#pragma unroll
      for (int r = 0; r < 4; r++)
        sa[f][r] = (key0 + r <= qrow) ? sa[f][r] * 0.125f : -1e30f;
    }
    // ---- online softmax for q=qrow (reduce over hi groups) ----
    float pmax = sa[0][0];
#pragma unroll
    for (int f = 0; f < 4; f++)
#pragma unroll
      for (int r = 0; r < 4; r++) pmax = fmaxf(pmax, sa[f][r]);
    pmax = fmaxf(pmax, __shfl_xor(pmax, 16, 64));
    pmax = fmaxf(pmax, __shfl_xor(pmax, 32, 64));
    float mnew = fmaxf(m_r, pmax);
    float corr = __expf(m_r - mnew);
    m_r = mnew;
    float psum = 0.f;
    float p[4][4];
#pragma unroll
    for (int f = 0; f < 4; f++)
#pragma unroll
      for (int r = 0; r < 4; r++){
        float pv = __expf(sa[f][r] - mnew);
        p[f][r] = pv;
        psum += pv;
      }
    psum += __shfl_xor(psum, 16, 64);
    psum += __shfl_xor(psum, 32, 64);
    l_r = l_r * corr + psum;
    // ---- P[q=lo][k] -> per-wave LDS, read back as A-frags ----
#pragma unroll
    for (int f = 0; f < 4; f++)
#pragma unroll
      for (int r = 0; r < 4; r++){
        int k = f * 16 + hi * 4 + r;
        *(u16*)((char*)&Ps[w][0] + lo * 144 + k * 2) = f2bf(p[f][r]);
      }
    // ---- rescale O ----
    float corr_q[4];
#pragma unroll
    for (int r = 0; r < 4; r++) corr_q[r] = __shfl(corr, hi * 4 + r, 64);
#pragma unroll
    for (int fd = 0; fd < 4; fd++)
#pragma unroll
      for (int r = 0; r < 4; r++) o[fd][r] *= corr_q[r];
    bf16x8 pa[2];
#pragma unroll
    for (int c = 0; c < 2; c++)
      pa[c] = *(const bf16x8*)((const char*)&Ps[w][0] + lo * 144 + c * 64 + hi * 16);
    // ---- O += P V ----
#pragma unroll
    for (int fd = 0; fd < 4; fd++)
#pragma unroll
      for (int c = 0; c < 2; c++)
        o[fd] = __builtin_amdgcn_mfma_f32_16x16x32_bf16(pa[c], vb[c][fd], o[fd], 0, 0, 0);
    __syncthreads();   // drains DMA (vmcnt) + P lds; buf[cur^1] ready
    cur ^= 1;
  }
  // ---- normalize + store: row q=hi*4+r, col d=fd*16+lo ----
  float linv = 1.0f / l_r;
  float inv_q[4];
#pragma unroll
  for (int r = 0; r < 4; r++) inv_q[r] = __shfl(linv, hi * 4 + r, 64);
#pragma unroll
  for (int r = 0; r < 4; r++){
    int srow = q0 + w * 16 + hi * 4 + r;
    u16* orow = Oout + (size_t)(b * S + srow) * 1024 + h * 64;
#pragma unroll
    for (int fd = 0; fd < 4; fd++)
      orow[fd * 16 + lo] = f2bf(o[fd][r] * inv_q[r]);
  }
}

extern "C" void kernel_launch(void* const* d_in, const int* in_sizes, int n_in,
                              void* d_out, int out_size, void* d_ws, size_t ws_size,
                              hipStream_t stream){
  const float* x     = (const float*)d_in[0];
  const float* w_qkv = (const float*)d_in[1];
  const float* b_qkv = (const float*)d_in[2];
  const float* w_out = (const float*)d_in[3];
  const float* b_out = (const float*)d_in[4];
  const float* cosb  = (const float*)d_in[5];
  const float* sinb  = (const float*)d_in[6];
  // d_in[7] = mask: causal, implemented analytically.
  float* out = (float*)d_out;
  char* ws = (char*)d_ws;
  u16* qkv  = (u16*)(ws);               // bf16 [4096][3072]   25.2 MB
  u16* attn = (u16*)(ws + 25165824);    // bf16 [4096][1024]    8.4 MB
  u16* wT2  = (u16*)(ws + 33554432);    // w_out^T bf16 [1024][1024]  2.1 MB
  u16* wT1  = (u16*)(ws + 35651584);    // w_qkv^T bf16 [3072][1024]  6.3 MB
  u16* vT   = (u16*)(ws + 35651584);    // vT [32][64][2048] 8.4 MB — overlaps
                                        // wT1 (dead after GEMM1)

  transpose64<<<dim3(48, 16), 256, 0, stream>>>(w_qkv, wT1, 1024, 3072);
  transpose64<<<dim3(16, 16), 256, 0, stream>>>(w_out, wT2, 1024, 1024);
  gemm_bt<true , false><<<dim3(24, 32), 256, 0, stream>>>(x,    wT1, b_qkv, qkv, 4096, 3072, 1024);
  rope_inplace<<<8192, 256, 0, stream>>>(qkv, cosb, sinb);
  v_transpose<<<dim3(32, 32), 256, 0, stream>>>(qkv, vT);
  flash_attn<<<dim3(32, 32), 256, 0, stream>>>(qkv, vT, attn);
  gemm_bt<false, true ><<<dim3(8, 32), 256, 0, stream>>>(attn, wT2, b_out, out, 4096, 1024, 1024);
}